// Round 1
// baseline (415.778 us; speedup 1.0000x reference)
//
#include <hip/hip_runtime.h>
#include <math.h>

// Problem constants: EMBED=256, HEADS=8, LEVELS=1, POINTS=4, QUEUE=2, 200x200
#define NQ    40000
#define EMB   256
#define NHEAD 8
#define HDIM  32
#define HB    200
#define WB    200
#define NCOL  192     // 128 off cols + 64 aw cols

typedef __attribute__((ext_vector_type(8))) __bf16 bf16x8;
typedef __attribute__((ext_vector_type(4))) float f32x4;

static __device__ __forceinline__ unsigned short f2bf(float f) {
  unsigned u = __float_as_uint(f);
  u = u + 0x7fffu + ((u >> 16) & 1u);   // round-to-nearest-even
  return (unsigned short)(u >> 16);
}
static __device__ __forceinline__ float bf2f(unsigned short s) {
  return __uint_as_float(((unsigned)s) << 16);
}

// ---------------------------------------------------------------------------
// conv_w: transposed bf16 weights + combined bias (tiny, one-shot)
// ---------------------------------------------------------------------------
__global__ __launch_bounds__(256) void conv_w(
    const float* __restrict__ W_off, const float* __restrict__ b_off,
    const float* __restrict__ W_attn, const float* __restrict__ b_attn,
    const float* __restrict__ W_val, const float* __restrict__ W_out,
    unsigned short* __restrict__ Wc1t, unsigned short* __restrict__ Wvt,
    unsigned short* __restrict__ Wot, float* __restrict__ bc1)
{
  int idx = blockIdx.x * 256 + threadIdx.x;
  if (idx < 98304) {                       // Wc1t [192][512]
    int n = idx >> 9, k = idx & 511;
    float v = (n < 128) ? W_off[(size_t)k * 128 + n] : W_attn[(size_t)k * 64 + (n - 128)];
    Wc1t[idx] = f2bf(v);
  } else if (idx < 163840) {               // Wvt [256][256]
    int j = idx - 98304;
    int n = j >> 8, k = j & 255;
    Wvt[j] = f2bf(W_val[(size_t)k * 256 + n]);
  } else if (idx < 229376) {               // Wot [256][256]
    int j = idx - 163840;
    int n = j >> 8, k = j & 255;
    Wot[j] = f2bf(W_out[(size_t)k * 256 + n]);
  } else if (idx < 229568) {               // bc1 [192]
    int n = idx - 229376;
    bc1[n] = (n < 128) ? b_off[n] : b_attn[n - 128];
  }
}

// ---------------------------------------------------------------------------
// Barrier-free register GEMM: C[M x N] = A[M x K] @ Bt[N x K]^T + bias.
// NO LDS in the K-loop: B frags stream from global (L2-hot, <=196 KB working
// set), A frags load directly in MFMA A-layout (lane lr = row, quad = k/8).
// Block = 256 thr = 4 waves, 1m x 4n: BM = 32, wave tile 32 x N/4.
// (BM=32 doubles the grid vs the old BM=64/2m x 2n layout -> ~2x waves/CU;
//  the kernel is latency-bound at 22% occupancy, acc regs drop 48->24.)
// AMODE: 0 = A bf16 [M][K]; 1 = A fp32; 2 = synth q2 (value | query+qpos).
// OMODE: 0 = fp32 direct store (+resid); 1 = bf16 via LDS transpose.
// ---------------------------------------------------------------------------
template<int K, int N, int AMODE, int OMODE, bool RESID>
__global__ __launch_bounds__(256) void rb_gemm(
    const void* __restrict__ Aptr, const float* __restrict__ Aq,
    const float* __restrict__ Aqp, const unsigned short* __restrict__ Bt,
    const float* __restrict__ bias, const float* __restrict__ resid,
    void* __restrict__ outp)
{
  constexpr int NFR = N / 64;              // 16-col n-frags per wave
  constexpr int NP  = N + 8;
  constexpr int TRN = (OMODE == 1) ? 32 * NP : 64;
  __shared__ unsigned short trn[TRN];

  const int t = threadIdx.x;
  const int m0 = blockIdx.x * 32;
  const int wid = t >> 6, lane = t & 63;
  const int wn = wid * (N / 4);
  const int lr = lane & 15, quad = lane >> 4;
  const int arow0 = m0 + lr;

  f32x4 acc[2][NFR];
  #pragma unroll
  for (int i = 0; i < 2; i++)
    #pragma unroll
    for (int n = 0; n < NFR; n++) acc[i][n] = (f32x4){0.f, 0.f, 0.f, 0.f};

  #pragma unroll 2
  for (int k0 = 0; k0 < K; k0 += 32) {
    const int kf = k0 + quad * 8;
    bf16x8 bfr[NFR];
    #pragma unroll
    for (int n = 0; n < NFR; n++)
      bfr[n] = *(const bf16x8*)(Bt + (size_t)(wn + n * 16 + lr) * K + kf);

    bf16x8 af[2];
    if constexpr (AMODE == 0) {
      const unsigned short* A = (const unsigned short*)Aptr;
      #pragma unroll
      for (int i = 0; i < 2; i++)
        af[i] = *(const bf16x8*)(A + (size_t)(arow0 + i * 16) * K + kf);
    } else {
      #pragma unroll
      for (int i = 0; i < 2; i++) {
        const int row = arow0 + i * 16;
        float4 f0, f1;
        if constexpr (AMODE == 1) {
          const float* Av = (const float*)Aptr;
          f0 = *(const float4*)(Av + (size_t)row * K + kf);
          f1 = *(const float4*)(Av + (size_t)row * K + kf + 4);
        } else {
          if (k0 < 256) {
            const float* Av = (const float*)Aptr;
            f0 = *(const float4*)(Av + (size_t)row * 256 + kf);
            f1 = *(const float4*)(Av + (size_t)row * 256 + kf + 4);
          } else {
            const int kq = kf - 256;
            float4 x0 = *(const float4*)(Aq  + (size_t)row * 256 + kq);
            float4 y0 = *(const float4*)(Aqp + (size_t)row * 256 + kq);
            float4 x1 = *(const float4*)(Aq  + (size_t)row * 256 + kq + 4);
            float4 y1 = *(const float4*)(Aqp + (size_t)row * 256 + kq + 4);
            f0 = make_float4(x0.x + y0.x, x0.y + y0.y, x0.z + y0.z, x0.w + y0.w);
            f1 = make_float4(x1.x + y1.x, x1.y + y1.y, x1.z + y1.z, x1.w + y1.w);
          }
        }
        union { unsigned short us[8]; bf16x8 v; } u;
        u.us[0] = f2bf(f0.x); u.us[1] = f2bf(f0.y);
        u.us[2] = f2bf(f0.z); u.us[3] = f2bf(f0.w);
        u.us[4] = f2bf(f1.x); u.us[5] = f2bf(f1.y);
        u.us[6] = f2bf(f1.z); u.us[7] = f2bf(f1.w);
        af[i] = u.v;
      }
    }
    #pragma unroll
    for (int i = 0; i < 2; i++)
      #pragma unroll
      for (int n = 0; n < NFR; n++)
        acc[i][n] = __builtin_amdgcn_mfma_f32_16x16x32_bf16(af[i], bfr[n], acc[i][n], 0, 0, 0);
  }

  // epilogue: C/D layout col=lane&15, row=quad*4+reg
  if constexpr (OMODE == 0) {
    #pragma unroll
    for (int i = 0; i < 2; i++) {
      int rowb = m0 + i * 16 + quad * 4;
      #pragma unroll
      for (int n = 0; n < NFR; n++) {
        int col = wn + n * 16 + lr;
        float bsv = bias[col];
        #pragma unroll
        for (int r = 0; r < 4; r++) {
          int rr = rowb + r;
          float v = acc[i][n][r] + bsv;
          if (RESID) v += resid[(size_t)rr * N + col];
          ((float*)outp)[(size_t)rr * N + col] = v;
        }
      }
    }
  } else {
    // bf16 out via LDS transpose -> full-line uint4 stores
    #pragma unroll
    for (int i = 0; i < 2; i++) {
      #pragma unroll
      for (int n = 0; n < NFR; n++) {
        int col = wn + n * 16 + lr;
        float bsv = bias[col];
        #pragma unroll
        for (int r = 0; r < 4; r++) {
          int rl = i * 16 + quad * 4 + r;
          trn[rl * NP + col] = f2bf(acc[i][n][r] + bsv);
        }
      }
    }
    __syncthreads();
    constexpr int NCH = (32 * N) / 2048;   // uint4 chunks per thread
    #pragma unroll
    for (int l = 0; l < NCH; l++) {
      int c = t + l * 256;
      int row = c / (N / 8);
      int coloff = (c % (N / 8)) * 8;
      uint4 d = *(const uint4*)(trn + row * NP + coloff);
      *(uint4*)((unsigned short*)outp + (size_t)(m0 + row) * N + coloff) = d;
    }
  }
}

// ---------------------------------------------------------------------------
// K3: deformable sampling + queue mean. 2 queries/block. raw1 bf16.
// ---------------------------------------------------------------------------
__global__ __launch_bounds__(256) void k3_sample(
    const unsigned short* __restrict__ raw1, const float* __restrict__ refp,
    const unsigned short* __restrict__ v, unsigned short* __restrict__ msd)
{
  __shared__ int4   sidx[2][64];
  __shared__ float4 swgt[2][64];
  const int t = threadIdx.x;
  const int q0 = blockIdx.x * 2;

  if (t < 128) {
    const int s = t >> 6, e = t & 63;
    const int b = e >> 5, h = (e >> 2) & 7, p = e & 3;
    const int q = q0 + s;
    const unsigned short* r = raw1 + (size_t)q * NCOL;
    float ox = bf2f(r[h * 16 + b * 8 + p * 2 + 0]);
    float oy = bf2f(r[h * 16 + b * 8 + p * 2 + 1]);
    float l0 = bf2f(r[128 + h * 8 + b * 4 + 0]);
    float l1 = bf2f(r[128 + h * 8 + b * 4 + 1]);
    float l2 = bf2f(r[128 + h * 8 + b * 4 + 2]);
    float l3 = bf2f(r[128 + h * 8 + b * 4 + 3]);
    float mx = fmaxf(fmaxf(l0, l1), fmaxf(l2, l3));
    float e0 = expf(l0 - mx), e1 = expf(l1 - mx);
    float e2 = expf(l2 - mx), e3 = expf(l3 - mx);
    float ssum = e0 + e1 + e2 + e3;
    float ep = (p == 0) ? e0 : (p == 1) ? e1 : (p == 2) ? e2 : e3;
    float aw = ep / ssum * 0.5f;          // fold queue-mean 0.5
    float rx = refp[((size_t)b * NQ + q) * 2 + 0];
    float ry = refp[((size_t)b * NQ + q) * 2 + 1];
    float px = rx * (float)WB + ox - 0.5f;
    float py = ry * (float)HB + oy - 0.5f;
    float x0f = floorf(px), y0f = floorf(py);
    float lx = px - x0f, ly = py - y0f;
    int x0 = (int)x0f, y0 = (int)y0f, x1 = x0 + 1, y1 = y0 + 1;
    int x0c = min(max(x0, 0), WB - 1), x1c = min(max(x1, 0), WB - 1);
    int y0c = min(max(y0, 0), HB - 1), y1c = min(max(y1, 0), HB - 1);
    float vx0 = ((unsigned)x0 < (unsigned)WB) ? 1.f : 0.f;
    float vx1 = ((unsigned)x1 < (unsigned)WB) ? 1.f : 0.f;
    float vy0 = ((unsigned)y0 < (unsigned)HB) ? 1.f : 0.f;
    float vy1 = ((unsigned)y1 < (unsigned)HB) ? 1.f : 0.f;
    const int pb = b * NQ;
    const int hb = h * HDIM;
    int4 ix;
    ix.x = (pb + y0c * WB + x0c) * EMB + hb;
    ix.y = (pb + y0c * WB + x1c) * EMB + hb;
    ix.z = (pb + y1c * WB + x0c) * EMB + hb;
    ix.w = (pb + y1c * WB + x1c) * EMB + hb;
    float4 wv;
    wv.x = aw * (1.f - lx) * (1.f - ly) * vx0 * vy0;
    wv.y = aw * lx * (1.f - ly) * vx1 * vy0;
    wv.z = aw * (1.f - lx) * ly * vx0 * vy1;
    wv.w = aw * lx * ly * vx1 * vy1;
    sidx[s][e] = ix;
    swgt[s][e] = wv;
  }
  __syncthreads();

  const int s = t >> 7, u = t & 127;
  const int h = u >> 4, d2 = u & 15;
  const unsigned short* vd = v + d2 * 2;
  float a0 = 0.f, a1 = 0.f;
  #pragma unroll
  for (int b = 0; b < 2; b++) {
    #pragma unroll
    for (int p = 0; p < 4; p++) {
      int ent = b * 32 + h * 4 + p;
      int4 ix = sidx[s][ent];
      float4 wv = swgt[s][ent];
      unsigned c00 = *(const unsigned*)(vd + ix.x);
      unsigned c10 = *(const unsigned*)(vd + ix.y);
      unsigned c01 = *(const unsigned*)(vd + ix.z);
      unsigned c11 = *(const unsigned*)(vd + ix.w);
      a0 += wv.x * __uint_as_float(c00 << 16);
      a1 += wv.x * __uint_as_float(c00 & 0xffff0000u);
      a0 += wv.y * __uint_as_float(c10 << 16);
      a1 += wv.y * __uint_as_float(c10 & 0xffff0000u);
      a0 += wv.z * __uint_as_float(c01 << 16);
      a1 += wv.z * __uint_as_float(c01 & 0xffff0000u);
      a0 += wv.w * __uint_as_float(c11 << 16);
      a1 += wv.w * __uint_as_float(c11 & 0xffff0000u);
    }
  }
  unsigned pack = ((unsigned)f2bf(a1) << 16) | (unsigned)f2bf(a0);
  *(unsigned*)(msd + (size_t)(q0 + s) * EMB + h * HDIM + d2 * 2) = pack;
}

// ---------------------------------------------------------------------------
extern "C" void kernel_launch(void* const* d_in, const int* in_sizes, int n_in,
                              void* d_out, int out_size, void* d_ws, size_t ws_size,
                              hipStream_t stream) {
  const float* query     = (const float*)d_in[0];
  const float* query_pos = (const float*)d_in[1];
  const float* value     = (const float*)d_in[2];
  const float* refp      = (const float*)d_in[3];
  // d_in[4]: spatial_shapes constant [200,200]
  const float* W_off  = (const float*)d_in[5];
  const float* b_off  = (const float*)d_in[6];
  const float* W_attn = (const float*)d_in[7];
  const float* b_attn = (const float*)d_in[8];
  const float* W_val  = (const float*)d_in[9];
  const float* b_val  = (const float*)d_in[10];
  const float* W_out  = (const float*)d_in[11];
  const float* b_out  = (const float*)d_in[12];
  float* out = (float*)d_out;

  char* ws = (char*)d_ws;
  unsigned short* raw1 = (unsigned short*)(ws);            // 40000*192*2 = 15,360,000
  unsigned short* vout = (unsigned short*)(ws + 15360000); // 80000*256*2 = 40,960,000
  unsigned short* msdb = (unsigned short*)(ws + 56320000); // 40000*256*2 = 20,480,000
  unsigned short* Wc1t = (unsigned short*)(ws + 76800000); // 192*512*2
  unsigned short* Wvt  = (unsigned short*)(ws + 76996608); // 256*256*2
  unsigned short* Wot  = (unsigned short*)(ws + 77127680); // 256*256*2
  float*          bc1  = (float*)(ws + 77258752);          // 192*4

  hipLaunchKernelGGL(conv_w, dim3(897), dim3(256), 0, stream,
                     W_off, b_off, W_attn, b_attn, W_val, W_out, Wc1t, Wvt, Wot, bc1);

  // k1: raw1 = q2 @ [W_off|W_attn] + bc1  (40000x512 @ 512x192), synth A, bf16 out
  hipLaunchKernelGGL((rb_gemm<512, 192, 2, 1, false>),
                     dim3(1250), dim3(256), 0, stream,
                     (const void*)value, query, query_pos, Wc1t, bc1,
                     (const float*)nullptr, (void*)raw1);
  // k2: v = value @ W_val + b_val  (80000x256 @ 256x256), fp32 A, bf16 out
  hipLaunchKernelGGL((rb_gemm<256, 256, 1, 1, false>),
                     dim3(2500), dim3(256), 0, stream,
                     (const void*)value, (const float*)nullptr, (const float*)nullptr,
                     Wvt, b_val, (const float*)nullptr, (void*)vout);
  // k3: sampling + queue mean -> msd bf16
  hipLaunchKernelGGL(k3_sample, dim3(NQ / 2), dim3(256), 0, stream,
                     raw1, refp, vout, msdb);
  // k4: out = msd @ W_out + b_out + query  (40000x256 @ 256x256), fp32 A=bf16, fp32 out + resid
  hipLaunchKernelGGL((rb_gemm<256, 256, 0, 0, true>),
                     dim3(1250), dim3(256), 0, stream,
                     (const void*)msdb, (const float*)nullptr, (const float*)nullptr,
                     Wot, b_out, query, (void*)out);
}

// Round 2
// 408.525 us; speedup vs baseline: 1.0178x; 1.0178x over previous
//
#include <hip/hip_runtime.h>
#include <math.h>

// Problem constants: EMBED=256, HEADS=8, LEVELS=1, POINTS=4, QUEUE=2, 200x200
#define NQ    40000
#define EMB   256
#define NHEAD 8
#define HDIM  32
#define HB    200
#define WB    200
#define NCOL  192     // 128 off cols + 64 aw cols

typedef __attribute__((ext_vector_type(8))) __bf16 bf16x8;
typedef __attribute__((ext_vector_type(4))) float f32x4;

static __device__ __forceinline__ unsigned short f2bf(float f) {
  unsigned u = __float_as_uint(f);
  u = u + 0x7fffu + ((u >> 16) & 1u);   // round-to-nearest-even
  return (unsigned short)(u >> 16);
}
static __device__ __forceinline__ float bf2f(unsigned short s) {
  return __uint_as_float(((unsigned)s) << 16);
}

// ---------------------------------------------------------------------------
// conv_w: transposed bf16 weights + combined bias (tiny, one-shot)
// ---------------------------------------------------------------------------
__global__ __launch_bounds__(256) void conv_w(
    const float* __restrict__ W_off, const float* __restrict__ b_off,
    const float* __restrict__ W_attn, const float* __restrict__ b_attn,
    const float* __restrict__ W_val, const float* __restrict__ W_out,
    unsigned short* __restrict__ Wc1t, unsigned short* __restrict__ Wvt,
    unsigned short* __restrict__ Wot, float* __restrict__ bc1)
{
  int idx = blockIdx.x * 256 + threadIdx.x;
  if (idx < 98304) {                       // Wc1t [192][512]
    int n = idx >> 9, k = idx & 511;
    float v = (n < 128) ? W_off[(size_t)k * 128 + n] : W_attn[(size_t)k * 64 + (n - 128)];
    Wc1t[idx] = f2bf(v);
  } else if (idx < 163840) {               // Wvt [256][256]
    int j = idx - 98304;
    int n = j >> 8, k = j & 255;
    Wvt[j] = f2bf(W_val[(size_t)k * 256 + n]);
  } else if (idx < 229376) {               // Wot [256][256]
    int j = idx - 163840;
    int n = j >> 8, k = j & 255;
    Wot[j] = f2bf(W_out[(size_t)k * 256 + n]);
  } else if (idx < 229568) {               // bc1 [192]
    int n = idx - 229376;
    bc1[n] = (n < 128) ? b_off[n] : b_attn[n - 128];
  }
}

// ---------------------------------------------------------------------------
// cvt: one memory-bound pre-pass producing bf16 A-matrices so the GEMM
// K-loops carry ZERO conversion VALU (round-1 post-mortem: in-loop f2bf was
// 3x the MFMA cycles and got duplicated per wave).
//   vb   [80000][256] = bf16(value)            (A for k2; rows<40000 = k1 lo-K)
//   qqpb [40000][256] = bf16(query+query_pos)  (k1 hi-K)
// ---------------------------------------------------------------------------
__global__ __launch_bounds__(256) void cvt(
    const float* __restrict__ value, const float* __restrict__ query,
    const float* __restrict__ qpos, unsigned short* __restrict__ vb,
    unsigned short* __restrict__ qqpb)
{
  unsigned idx = blockIdx.x * 256 + threadIdx.x;   // 15000*256 = 3,840,000
  float4 f0, f1;
  unsigned short* dst;
  if (idx < 2560000u) {                            // vb: 80000*256/8 chunks
    const float* s = value + (size_t)idx * 8;
    f0 = *(const float4*)s;
    f1 = *(const float4*)(s + 4);
    dst = vb + (size_t)idx * 8;
  } else {                                         // qqpb: 40000*256/8 chunks
    unsigned j = idx - 2560000u;
    const float* sq = query + (size_t)j * 8;
    const float* sp = qpos + (size_t)j * 8;
    float4 a0 = *(const float4*)sq, a1 = *(const float4*)(sq + 4);
    float4 b0 = *(const float4*)sp, b1 = *(const float4*)(sp + 4);
    f0 = make_float4(a0.x + b0.x, a0.y + b0.y, a0.z + b0.z, a0.w + b0.w);
    f1 = make_float4(a1.x + b1.x, a1.y + b1.y, a1.z + b1.z, a1.w + b1.w);
    dst = qqpb + (size_t)j * 8;
  }
  union { unsigned short us[8]; uint4 v; } u;
  u.us[0] = f2bf(f0.x); u.us[1] = f2bf(f0.y);
  u.us[2] = f2bf(f0.z); u.us[3] = f2bf(f0.w);
  u.us[4] = f2bf(f1.x); u.us[5] = f2bf(f1.y);
  u.us[6] = f2bf(f1.z); u.us[7] = f2bf(f1.w);
  *(uint4*)dst = u.v;
}

// ---------------------------------------------------------------------------
// Barrier-free register GEMM: C[M x N] = A[M x K] @ Bt[N x K]^T + bias.
// NO LDS in the K-loop: B frags stream from global (L2-hot, <=196 KB working
// set), A frags load directly in MFMA A-layout (lane lr = row, quad = k/8).
// Block = 256 thr = 4 waves, 1m x 4n: BM = 32, wave tile 32 x N/4.
// All A paths are now bf16 (pre-converted by cvt) -> lean K-loop.
// AMODE: 0 = A bf16 [M][K]; 3 = split bf16: Aptr [M][256] k<256, Aq2 k>=256.
// OMODE: 0 = fp32 direct store (+resid); 1 = bf16 via LDS transpose.
// ---------------------------------------------------------------------------
template<int K, int N, int AMODE, int OMODE, bool RESID>
__global__ __launch_bounds__(256) void rb_gemm(
    const void* __restrict__ Aptr, const void* __restrict__ Aq2,
    const unsigned short* __restrict__ Bt,
    const float* __restrict__ bias, const float* __restrict__ resid,
    void* __restrict__ outp)
{
  constexpr int NFR = N / 64;              // 16-col n-frags per wave
  constexpr int NP  = N + 8;
  constexpr int TRN = (OMODE == 1) ? 32 * NP : 64;
  __shared__ unsigned short trn[TRN];

  const int t = threadIdx.x;
  const int m0 = blockIdx.x * 32;
  const int wid = t >> 6, lane = t & 63;
  const int wn = wid * (N / 4);
  const int lr = lane & 15, quad = lane >> 4;
  const int arow0 = m0 + lr;

  f32x4 acc[2][NFR];
  #pragma unroll
  for (int i = 0; i < 2; i++)
    #pragma unroll
    for (int n = 0; n < NFR; n++) acc[i][n] = (f32x4){0.f, 0.f, 0.f, 0.f};

  #pragma unroll 2
  for (int k0 = 0; k0 < K; k0 += 32) {
    const int kf = k0 + quad * 8;
    bf16x8 bfr[NFR];
    #pragma unroll
    for (int n = 0; n < NFR; n++)
      bfr[n] = *(const bf16x8*)(Bt + (size_t)(wn + n * 16 + lr) * K + kf);

    bf16x8 af[2];
    if constexpr (AMODE == 0) {
      const unsigned short* A = (const unsigned short*)Aptr;
      #pragma unroll
      for (int i = 0; i < 2; i++)
        af[i] = *(const bf16x8*)(A + (size_t)(arow0 + i * 16) * K + kf);
    } else {                               // AMODE == 3: split bf16 sources
      const unsigned short* A = (k0 < 256) ? (const unsigned short*)Aptr
                                           : (const unsigned short*)Aq2;
      const int kq = (k0 < 256) ? kf : kf - 256;
      #pragma unroll
      for (int i = 0; i < 2; i++)
        af[i] = *(const bf16x8*)(A + (size_t)(arow0 + i * 16) * 256 + kq);
    }
    #pragma unroll
    for (int i = 0; i < 2; i++)
      #pragma unroll
      for (int n = 0; n < NFR; n++)
        acc[i][n] = __builtin_amdgcn_mfma_f32_16x16x32_bf16(af[i], bfr[n], acc[i][n], 0, 0, 0);
  }

  // epilogue: C/D layout col=lane&15, row=quad*4+reg
  if constexpr (OMODE == 0) {
    #pragma unroll
    for (int i = 0; i < 2; i++) {
      int rowb = m0 + i * 16 + quad * 4;
      #pragma unroll
      for (int n = 0; n < NFR; n++) {
        int col = wn + n * 16 + lr;
        float bsv = bias[col];
        #pragma unroll
        for (int r = 0; r < 4; r++) {
          int rr = rowb + r;
          float v = acc[i][n][r] + bsv;
          if (RESID) v += resid[(size_t)rr * N + col];
          ((float*)outp)[(size_t)rr * N + col] = v;
        }
      }
    }
  } else {
    // bf16 out via LDS transpose -> full-line uint4 stores
    #pragma unroll
    for (int i = 0; i < 2; i++) {
      #pragma unroll
      for (int n = 0; n < NFR; n++) {
        int col = wn + n * 16 + lr;
        float bsv = bias[col];
        #pragma unroll
        for (int r = 0; r < 4; r++) {
          int rl = i * 16 + quad * 4 + r;
          trn[rl * NP + col] = f2bf(acc[i][n][r] + bsv);
        }
      }
    }
    __syncthreads();
    constexpr int NCH = (32 * N) / 2048;   // uint4 chunks per thread
    #pragma unroll
    for (int l = 0; l < NCH; l++) {
      int c = t + l * 256;
      int row = c / (N / 8);
      int coloff = (c % (N / 8)) * 8;
      uint4 d = *(const uint4*)(trn + row * NP + coloff);
      *(uint4*)((unsigned short*)outp + (size_t)(m0 + row) * N + coloff) = d;
    }
  }
}

// ---------------------------------------------------------------------------
// K3: deformable sampling + queue mean. 2 queries/block. raw1 bf16.
// ---------------------------------------------------------------------------
__global__ __launch_bounds__(256) void k3_sample(
    const unsigned short* __restrict__ raw1, const float* __restrict__ refp,
    const unsigned short* __restrict__ v, unsigned short* __restrict__ msd)
{
  __shared__ int4   sidx[2][64];
  __shared__ float4 swgt[2][64];
  const int t = threadIdx.x;
  const int q0 = blockIdx.x * 2;

  if (t < 128) {
    const int s = t >> 6, e = t & 63;
    const int b = e >> 5, h = (e >> 2) & 7, p = e & 3;
    const int q = q0 + s;
    const unsigned short* r = raw1 + (size_t)q * NCOL;
    float ox = bf2f(r[h * 16 + b * 8 + p * 2 + 0]);
    float oy = bf2f(r[h * 16 + b * 8 + p * 2 + 1]);
    float l0 = bf2f(r[128 + h * 8 + b * 4 + 0]);
    float l1 = bf2f(r[128 + h * 8 + b * 4 + 1]);
    float l2 = bf2f(r[128 + h * 8 + b * 4 + 2]);
    float l3 = bf2f(r[128 + h * 8 + b * 4 + 3]);
    float mx = fmaxf(fmaxf(l0, l1), fmaxf(l2, l3));
    float e0 = expf(l0 - mx), e1 = expf(l1 - mx);
    float e2 = expf(l2 - mx), e3 = expf(l3 - mx);
    float ssum = e0 + e1 + e2 + e3;
    float ep = (p == 0) ? e0 : (p == 1) ? e1 : (p == 2) ? e2 : e3;
    float aw = ep / ssum * 0.5f;          // fold queue-mean 0.5
    float rx = refp[((size_t)b * NQ + q) * 2 + 0];
    float ry = refp[((size_t)b * NQ + q) * 2 + 1];
    float px = rx * (float)WB + ox - 0.5f;
    float py = ry * (float)HB + oy - 0.5f;
    float x0f = floorf(px), y0f = floorf(py);
    float lx = px - x0f, ly = py - y0f;
    int x0 = (int)x0f, y0 = (int)y0f, x1 = x0 + 1, y1 = y0 + 1;
    int x0c = min(max(x0, 0), WB - 1), x1c = min(max(x1, 0), WB - 1);
    int y0c = min(max(y0, 0), HB - 1), y1c = min(max(y1, 0), HB - 1);
    float vx0 = ((unsigned)x0 < (unsigned)WB) ? 1.f : 0.f;
    float vx1 = ((unsigned)x1 < (unsigned)WB) ? 1.f : 0.f;
    float vy0 = ((unsigned)y0 < (unsigned)HB) ? 1.f : 0.f;
    float vy1 = ((unsigned)y1 < (unsigned)HB) ? 1.f : 0.f;
    const int pb = b * NQ;
    const int hb = h * HDIM;
    int4 ix;
    ix.x = (pb + y0c * WB + x0c) * EMB + hb;
    ix.y = (pb + y0c * WB + x1c) * EMB + hb;
    ix.z = (pb + y1c * WB + x0c) * EMB + hb;
    ix.w = (pb + y1c * WB + x1c) * EMB + hb;
    float4 wv;
    wv.x = aw * (1.f - lx) * (1.f - ly) * vx0 * vy0;
    wv.y = aw * lx * (1.f - ly) * vx1 * vy0;
    wv.z = aw * (1.f - lx) * ly * vx0 * vy1;
    wv.w = aw * lx * ly * vx1 * vy1;
    sidx[s][e] = ix;
    swgt[s][e] = wv;
  }
  __syncthreads();

  const int s = t >> 7, u = t & 127;
  const int h = u >> 4, d2 = u & 15;
  const unsigned short* vd = v + d2 * 2;
  float a0 = 0.f, a1 = 0.f;
  #pragma unroll
  for (int b = 0; b < 2; b++) {
    #pragma unroll
    for (int p = 0; p < 4; p++) {
      int ent = b * 32 + h * 4 + p;
      int4 ix = sidx[s][ent];
      float4 wv = swgt[s][ent];
      unsigned c00 = *(const unsigned*)(vd + ix.x);
      unsigned c10 = *(const unsigned*)(vd + ix.y);
      unsigned c01 = *(const unsigned*)(vd + ix.z);
      unsigned c11 = *(const unsigned*)(vd + ix.w);
      a0 += wv.x * __uint_as_float(c00 << 16);
      a1 += wv.x * __uint_as_float(c00 & 0xffff0000u);
      a0 += wv.y * __uint_as_float(c10 << 16);
      a1 += wv.y * __uint_as_float(c10 & 0xffff0000u);
      a0 += wv.z * __uint_as_float(c01 << 16);
      a1 += wv.z * __uint_as_float(c01 & 0xffff0000u);
      a0 += wv.w * __uint_as_float(c11 << 16);
      a1 += wv.w * __uint_as_float(c11 & 0xffff0000u);
    }
  }
  unsigned pack = ((unsigned)f2bf(a1) << 16) | (unsigned)f2bf(a0);
  *(unsigned*)(msd + (size_t)(q0 + s) * EMB + h * HDIM + d2 * 2) = pack;
}

// ---------------------------------------------------------------------------
extern "C" void kernel_launch(void* const* d_in, const int* in_sizes, int n_in,
                              void* d_out, int out_size, void* d_ws, size_t ws_size,
                              hipStream_t stream) {
  const float* query     = (const float*)d_in[0];
  const float* query_pos = (const float*)d_in[1];
  const float* value     = (const float*)d_in[2];
  const float* refp      = (const float*)d_in[3];
  // d_in[4]: spatial_shapes constant [200,200]
  const float* W_off  = (const float*)d_in[5];
  const float* b_off  = (const float*)d_in[6];
  const float* W_attn = (const float*)d_in[7];
  const float* b_attn = (const float*)d_in[8];
  const float* W_val  = (const float*)d_in[9];
  const float* b_val  = (const float*)d_in[10];
  const float* W_out  = (const float*)d_in[11];
  const float* b_out  = (const float*)d_in[12];
  float* out = (float*)d_out;

  char* ws = (char*)d_ws;
  unsigned short* raw1 = (unsigned short*)(ws);             // 40000*192*2 = 15,360,000
  unsigned short* vout = (unsigned short*)(ws + 15360000);  // 80000*256*2 = 40,960,000
  unsigned short* vb   = (unsigned short*)(ws + 56320000);  // 80000*256*2 = 40,960,000 (dead after k2)
  unsigned short* qqpb = (unsigned short*)(ws + 97280000);  // 40000*256*2 = 20,480,000 (dead after k1)
  unsigned short* msdb = (unsigned short*)(ws + 97280000);  // aliases qqpb (written in k3, after k1)
  unsigned short* Wc1t = (unsigned short*)(ws + 117760000); // 192*512*2
  unsigned short* Wvt  = (unsigned short*)(ws + 117956608); // 256*256*2
  unsigned short* Wot  = (unsigned short*)(ws + 118087680); // 256*256*2
  float*          bc1  = (float*)(ws + 118218752);          // 192*4

  hipLaunchKernelGGL(conv_w, dim3(897), dim3(256), 0, stream,
                     W_off, b_off, W_attn, b_attn, W_val, W_out, Wc1t, Wvt, Wot, bc1);
  // cvt: bf16 pre-conversion of all GEMM A-matrices (memory-bound, ~225 MB)
  hipLaunchKernelGGL(cvt, dim3(15000), dim3(256), 0, stream,
                     value, query, query_pos, vb, qqpb);

  // k1: raw1 = q2 @ [W_off|W_attn] + bc1  (40000x512 @ 512x192), split bf16 A, bf16 out
  hipLaunchKernelGGL((rb_gemm<512, 192, 3, 1, false>),
                     dim3(1250), dim3(256), 0, stream,
                     (const void*)vb, (const void*)qqpb, Wc1t, bc1,
                     (const float*)nullptr, (void*)raw1);
  // k2: v = value @ W_val + b_val  (80000x256 @ 256x256), bf16 A, bf16 out
  hipLaunchKernelGGL((rb_gemm<256, 256, 0, 1, false>),
                     dim3(2500), dim3(256), 0, stream,
                     (const void*)vb, (const void*)nullptr, Wvt, b_val,
                     (const float*)nullptr, (void*)vout);
  // k3: sampling + queue mean -> msd bf16
  hipLaunchKernelGGL(k3_sample, dim3(NQ / 2), dim3(256), 0, stream,
                     raw1, refp, vout, msdb);
  // k4: out = msd @ W_out + b_out + query  (40000x256 @ 256x256), bf16 A, fp32 out + resid
  hipLaunchKernelGGL((rb_gemm<256, 256, 0, 0, true>),
                     dim3(1250), dim3(256), 0, stream,
                     (const void*)msdb, (const void*)nullptr, Wot, b_out,
                     query, (void*)out);
}

// Round 3
// 374.825 us; speedup vs baseline: 1.1093x; 1.0899x over previous
//
#include <hip/hip_runtime.h>
#include <math.h>

// Problem constants: EMBED=256, HEADS=8, LEVELS=1, POINTS=4, QUEUE=2, 200x200
#define NQ    40000
#define EMB   256
#define NHEAD 8
#define HDIM  32
#define HB    200
#define WB    200
#define NCOL  192     // 128 off cols + 64 aw cols

typedef __attribute__((ext_vector_type(8))) __bf16 bf16x8;
typedef __attribute__((ext_vector_type(4))) float f32x4;

static __device__ __forceinline__ unsigned short f2bf(float f) {
  unsigned u = __float_as_uint(f);
  u = u + 0x7fffu + ((u >> 16) & 1u);   // round-to-nearest-even
  return (unsigned short)(u >> 16);
}
static __device__ __forceinline__ float bf2f(unsigned short s) {
  return __uint_as_float(((unsigned)s) << 16);
}

// ---------------------------------------------------------------------------
// conv_w: transposed bf16 weights + combined bias (tiny, one-shot)
// ---------------------------------------------------------------------------
__global__ __launch_bounds__(256) void conv_w(
    const float* __restrict__ W_off, const float* __restrict__ b_off,
    const float* __restrict__ W_attn, const float* __restrict__ b_attn,
    const float* __restrict__ W_val, const float* __restrict__ W_out,
    unsigned short* __restrict__ Wc1t, unsigned short* __restrict__ Wvt,
    unsigned short* __restrict__ Wot, float* __restrict__ bc1)
{
  int idx = blockIdx.x * 256 + threadIdx.x;
  if (idx < 98304) {                       // Wc1t [192][512]
    int n = idx >> 9, k = idx & 511;
    float v = (n < 128) ? W_off[(size_t)k * 128 + n] : W_attn[(size_t)k * 64 + (n - 128)];
    Wc1t[idx] = f2bf(v);
  } else if (idx < 163840) {               // Wvt [256][256]
    int j = idx - 98304;
    int n = j >> 8, k = j & 255;
    Wvt[j] = f2bf(W_val[(size_t)k * 256 + n]);
  } else if (idx < 229376) {               // Wot [256][256]
    int j = idx - 163840;
    int n = j >> 8, k = j & 255;
    Wot[j] = f2bf(W_out[(size_t)k * 256 + n]);
  } else if (idx < 229568) {               // bc1 [192]
    int n = idx - 229376;
    bc1[n] = (n < 128) ? b_off[n] : b_attn[n - 128];
  }
}

// ---------------------------------------------------------------------------
// Register GEMM: C[M x N] = A[M x K] @ Bt[N x K]^T + bias.
// B frags stream from global (L2-hot, <=196 KB). A path:
//   AMODE 0: A bf16 [M][K], direct global frag loads (16 KB tile, L1-hot).
//   AMODE 1: A fp32 [M][K], staged ONCE per block -> bf16 LDS tile.
//   AMODE 2: synth q2 = [value | query+query_pos], staged ONCE -> LDS.
// LDS A-tile is XOR-swizzled in 16B chunks (chunk c stored at c^(r&7)) so the
// K-loop's ds_read_b128 A-frag reads (16 lanes = 16 rows, same chunk) hit
// 8 distinct 16B slots = 2-way conflict = free (m136). Staging converts each
// element exactly once (round-1 lesson: in-loop f2bf was 3x MFMA cycles and
// duplicated 4x across waves; round-2 lesson: a separate cvt pass costs a
// full latency-bound memory pass, 68 us).
// Block = 256 thr = 4 waves, 1m x 4n: BM = 32, wave tile 32 x N/4.
// OMODE: 0 = fp32 direct store (+resid); 1 = bf16 via LDS transpose (buffer
// unioned with the A-tile; barrier separates the two uses).
// ---------------------------------------------------------------------------
template<int K, int N, int AMODE, int OMODE, bool RESID>
__global__ __launch_bounds__(256) void rb_gemm(
    const void* __restrict__ Aptr, const void* __restrict__ Aq2a,
    const void* __restrict__ Aq2b, const unsigned short* __restrict__ Bt,
    const float* __restrict__ bias, const float* __restrict__ resid,
    void* __restrict__ outp)
{
  constexpr int NFR = N / 64;              // 16-col n-frags per wave
  constexpr int NP  = N + 8;
  constexpr int ATB = (AMODE != 0) ? 32 * K * 2 : 0;      // A-tile bytes
  constexpr int TRB = (OMODE == 1) ? 32 * NP * 2 : 0;     // transpose bytes
  constexpr int MXB = (ATB > TRB) ? ATB : TRB;
  constexpr int LDSB = (MXB > 64) ? MXB : 64;
  __shared__ __align__(16) char lds[LDSB];
  unsigned short* trn = (unsigned short*)lds;

  const int t = threadIdx.x;
  const int m0 = blockIdx.x * 32;
  const int wid = t >> 6, lane = t & 63;
  const int wn = wid * (N / 4);
  const int lr = lane & 15, quad = lane >> 4;

  // ---- A staging: fp32 global -> bf16 LDS tile, once per block ----
  if constexpr (AMODE != 0) {
    constexpr int CH  = K / 8;             // 16B chunks per row
    constexpr int NST = (32 * CH) / 256;   // chunks per thread
    #pragma unroll
    for (int l = 0; l < NST; l++) {
      int ci = t + l * 256;
      int r = ci / CH, c = ci % CH;
      int grow = m0 + r;
      float4 f0, f1;
      if constexpr (AMODE == 1) {
        const float* s = (const float*)Aptr + (size_t)grow * K + c * 8;
        f0 = *(const float4*)s; f1 = *(const float4*)(s + 4);
      } else {
        if (c < 32) {                      // lo-K: value
          const float* s = (const float*)Aptr + (size_t)grow * 256 + c * 8;
          f0 = *(const float4*)s; f1 = *(const float4*)(s + 4);
        } else {                           // hi-K: query + query_pos
          const float* sq = (const float*)Aq2a + (size_t)grow * 256 + (c - 32) * 8;
          const float* sp = (const float*)Aq2b + (size_t)grow * 256 + (c - 32) * 8;
          float4 a0 = *(const float4*)sq, a1 = *(const float4*)(sq + 4);
          float4 b0 = *(const float4*)sp, b1 = *(const float4*)(sp + 4);
          f0 = make_float4(a0.x + b0.x, a0.y + b0.y, a0.z + b0.z, a0.w + b0.w);
          f1 = make_float4(a1.x + b1.x, a1.y + b1.y, a1.z + b1.z, a1.w + b1.w);
        }
      }
      union { unsigned short us[8]; uint4 v; } u;
      u.us[0] = f2bf(f0.x); u.us[1] = f2bf(f0.y);
      u.us[2] = f2bf(f0.z); u.us[3] = f2bf(f0.w);
      u.us[4] = f2bf(f1.x); u.us[5] = f2bf(f1.y);
      u.us[6] = f2bf(f1.z); u.us[7] = f2bf(f1.w);
      *(uint4*)(lds + (size_t)r * (K * 2) + ((c ^ (r & 7)) * 16)) = u.v;
    }
    __syncthreads();
  }

  f32x4 acc[2][NFR];
  #pragma unroll
  for (int i = 0; i < 2; i++)
    #pragma unroll
    for (int n = 0; n < NFR; n++) acc[i][n] = (f32x4){0.f, 0.f, 0.f, 0.f};

  #pragma unroll 2
  for (int k0 = 0; k0 < K; k0 += 32) {
    const int kf = k0 + quad * 8;
    bf16x8 bfr[NFR];
    #pragma unroll
    for (int n = 0; n < NFR; n++)
      bfr[n] = *(const bf16x8*)(Bt + (size_t)(wn + n * 16 + lr) * K + kf);

    bf16x8 af[2];
    if constexpr (AMODE == 0) {
      const unsigned short* A = (const unsigned short*)Aptr;
      #pragma unroll
      for (int i = 0; i < 2; i++)
        af[i] = *(const bf16x8*)(A + (size_t)(m0 + lr + i * 16) * K + kf);
    } else {
      const int cb = kf >> 3;              // chunk index = k0/8 + quad
      const int sw = (cb ^ (lr & 7)) * 16;
      #pragma unroll
      for (int i = 0; i < 2; i++)
        af[i] = *(const bf16x8*)(lds + (size_t)(lr + i * 16) * (K * 2) + sw);
    }
    #pragma unroll
    for (int i = 0; i < 2; i++)
      #pragma unroll
      for (int n = 0; n < NFR; n++)
        acc[i][n] = __builtin_amdgcn_mfma_f32_16x16x32_bf16(af[i], bfr[n], acc[i][n], 0, 0, 0);
  }

  // epilogue: C/D layout col=lane&15, row=quad*4+reg
  if constexpr (OMODE == 0) {
    #pragma unroll
    for (int i = 0; i < 2; i++) {
      int rowb = m0 + i * 16 + quad * 4;
      #pragma unroll
      for (int n = 0; n < NFR; n++) {
        int col = wn + n * 16 + lr;
        float bsv = bias[col];
        #pragma unroll
        for (int r = 0; r < 4; r++) {
          int rr = rowb + r;
          float v = acc[i][n][r] + bsv;
          if (RESID) v += resid[(size_t)rr * N + col];
          ((float*)outp)[(size_t)rr * N + col] = v;
        }
      }
    }
  } else {
    // bf16 out via LDS transpose -> full-line uint4 stores.
    if constexpr (AMODE != 0) __syncthreads();   // A-tile -> trn buffer reuse
    #pragma unroll
    for (int i = 0; i < 2; i++) {
      #pragma unroll
      for (int n = 0; n < NFR; n++) {
        int col = wn + n * 16 + lr;
        float bsv = bias[col];
        #pragma unroll
        for (int r = 0; r < 4; r++) {
          int rl = i * 16 + quad * 4 + r;
          trn[rl * NP + col] = f2bf(acc[i][n][r] + bsv);
        }
      }
    }
    __syncthreads();
    constexpr int NCH = (32 * N) / 2048;   // uint4 chunks per thread
    #pragma unroll
    for (int l = 0; l < NCH; l++) {
      int c = t + l * 256;
      int row = c / (N / 8);
      int coloff = (c % (N / 8)) * 8;
      uint4 d = *(const uint4*)(trn + row * NP + coloff);
      *(uint4*)((unsigned short*)outp + (size_t)(m0 + row) * N + coloff) = d;
    }
  }
}

// ---------------------------------------------------------------------------
// K3: deformable sampling + queue mean. 2 queries/block. raw1 bf16.
// ---------------------------------------------------------------------------
__global__ __launch_bounds__(256) void k3_sample(
    const unsigned short* __restrict__ raw1, const float* __restrict__ refp,
    const unsigned short* __restrict__ v, unsigned short* __restrict__ msd)
{
  __shared__ int4   sidx[2][64];
  __shared__ float4 swgt[2][64];
  const int t = threadIdx.x;
  const int q0 = blockIdx.x * 2;

  if (t < 128) {
    const int s = t >> 6, e = t & 63;
    const int b = e >> 5, h = (e >> 2) & 7, p = e & 3;
    const int q = q0 + s;
    const unsigned short* r = raw1 + (size_t)q * NCOL;
    float ox = bf2f(r[h * 16 + b * 8 + p * 2 + 0]);
    float oy = bf2f(r[h * 16 + b * 8 + p * 2 + 1]);
    float l0 = bf2f(r[128 + h * 8 + b * 4 + 0]);
    float l1 = bf2f(r[128 + h * 8 + b * 4 + 1]);
    float l2 = bf2f(r[128 + h * 8 + b * 4 + 2]);
    float l3 = bf2f(r[128 + h * 8 + b * 4 + 3]);
    float mx = fmaxf(fmaxf(l0, l1), fmaxf(l2, l3));
    float e0 = expf(l0 - mx), e1 = expf(l1 - mx);
    float e2 = expf(l2 - mx), e3 = expf(l3 - mx);
    float ssum = e0 + e1 + e2 + e3;
    float ep = (p == 0) ? e0 : (p == 1) ? e1 : (p == 2) ? e2 : e3;
    float aw = ep / ssum * 0.5f;          // fold queue-mean 0.5
    float rx = refp[((size_t)b * NQ + q) * 2 + 0];
    float ry = refp[((size_t)b * NQ + q) * 2 + 1];
    float px = rx * (float)WB + ox - 0.5f;
    float py = ry * (float)HB + oy - 0.5f;
    float x0f = floorf(px), y0f = floorf(py);
    float lx = px - x0f, ly = py - y0f;
    int x0 = (int)x0f, y0 = (int)y0f, x1 = x0 + 1, y1 = y0 + 1;
    int x0c = min(max(x0, 0), WB - 1), x1c = min(max(x1, 0), WB - 1);
    int y0c = min(max(y0, 0), HB - 1), y1c = min(max(y1, 0), HB - 1);
    float vx0 = ((unsigned)x0 < (unsigned)WB) ? 1.f : 0.f;
    float vx1 = ((unsigned)x1 < (unsigned)WB) ? 1.f : 0.f;
    float vy0 = ((unsigned)y0 < (unsigned)HB) ? 1.f : 0.f;
    float vy1 = ((unsigned)y1 < (unsigned)HB) ? 1.f : 0.f;
    const int pb = b * NQ;
    const int hb = h * HDIM;
    int4 ix;
    ix.x = (pb + y0c * WB + x0c) * EMB + hb;
    ix.y = (pb + y0c * WB + x1c) * EMB + hb;
    ix.z = (pb + y1c * WB + x0c) * EMB + hb;
    ix.w = (pb + y1c * WB + x1c) * EMB + hb;
    float4 wv;
    wv.x = aw * (1.f - lx) * (1.f - ly) * vx0 * vy0;
    wv.y = aw * lx * (1.f - ly) * vx1 * vy0;
    wv.z = aw * (1.f - lx) * ly * vx0 * vy1;
    wv.w = aw * lx * ly * vx1 * vy1;
    sidx[s][e] = ix;
    swgt[s][e] = wv;
  }
  __syncthreads();

  const int s = t >> 7, u = t & 127;
  const int h = u >> 4, d2 = u & 15;
  const unsigned short* vd = v + d2 * 2;
  float a0 = 0.f, a1 = 0.f;
  #pragma unroll
  for (int b = 0; b < 2; b++) {
    #pragma unroll
    for (int p = 0; p < 4; p++) {
      int ent = b * 32 + h * 4 + p;
      int4 ix = sidx[s][ent];
      float4 wv = swgt[s][ent];
      unsigned c00 = *(const unsigned*)(vd + ix.x);
      unsigned c10 = *(const unsigned*)(vd + ix.y);
      unsigned c01 = *(const unsigned*)(vd + ix.z);
      unsigned c11 = *(const unsigned*)(vd + ix.w);
      a0 += wv.x * __uint_as_float(c00 << 16);
      a1 += wv.x * __uint_as_float(c00 & 0xffff0000u);
      a0 += wv.y * __uint_as_float(c10 << 16);
      a1 += wv.y * __uint_as_float(c10 & 0xffff0000u);
      a0 += wv.z * __uint_as_float(c01 << 16);
      a1 += wv.z * __uint_as_float(c01 & 0xffff0000u);
      a0 += wv.w * __uint_as_float(c11 << 16);
      a1 += wv.w * __uint_as_float(c11 & 0xffff0000u);
    }
  }
  unsigned pack = ((unsigned)f2bf(a1) << 16) | (unsigned)f2bf(a0);
  *(unsigned*)(msd + (size_t)(q0 + s) * EMB + h * HDIM + d2 * 2) = pack;
}

// ---------------------------------------------------------------------------
extern "C" void kernel_launch(void* const* d_in, const int* in_sizes, int n_in,
                              void* d_out, int out_size, void* d_ws, size_t ws_size,
                              hipStream_t stream) {
  const float* query     = (const float*)d_in[0];
  const float* query_pos = (const float*)d_in[1];
  const float* value     = (const float*)d_in[2];
  const float* refp      = (const float*)d_in[3];
  // d_in[4]: spatial_shapes constant [200,200]
  const float* W_off  = (const float*)d_in[5];
  const float* b_off  = (const float*)d_in[6];
  const float* W_attn = (const float*)d_in[7];
  const float* b_attn = (const float*)d_in[8];
  const float* W_val  = (const float*)d_in[9];
  const float* b_val  = (const float*)d_in[10];
  const float* W_out  = (const float*)d_in[11];
  const float* b_out  = (const float*)d_in[12];
  float* out = (float*)d_out;

  char* ws = (char*)d_ws;
  unsigned short* raw1 = (unsigned short*)(ws);            // 40000*192*2 = 15,360,000
  unsigned short* vout = (unsigned short*)(ws + 15360000); // 80000*256*2 = 40,960,000
  unsigned short* msdb = (unsigned short*)(ws + 56320000); // 40000*256*2 = 20,480,000
  unsigned short* Wc1t = (unsigned short*)(ws + 76800000); // 192*512*2
  unsigned short* Wvt  = (unsigned short*)(ws + 76996608); // 256*256*2
  unsigned short* Wot  = (unsigned short*)(ws + 77127680); // 256*256*2
  float*          bc1  = (float*)(ws + 77258752);          // 192*4

  hipLaunchKernelGGL(conv_w, dim3(897), dim3(256), 0, stream,
                     W_off, b_off, W_attn, b_attn, W_val, W_out, Wc1t, Wvt, Wot, bc1);

  // k1: raw1 = q2 @ [W_off|W_attn] + bc1  (40000x512 @ 512x192), staged synth A, bf16 out
  hipLaunchKernelGGL((rb_gemm<512, 192, 2, 1, false>),
                     dim3(1250), dim3(256), 0, stream,
                     (const void*)value, (const void*)query, (const void*)query_pos,
                     Wc1t, bc1, (const float*)nullptr, (void*)raw1);
  // k2: v = value @ W_val + b_val  (80000x256 @ 256x256), staged fp32 A, bf16 out
  hipLaunchKernelGGL((rb_gemm<256, 256, 1, 1, false>),
                     dim3(2500), dim3(256), 0, stream,
                     (const void*)value, (const void*)nullptr, (const void*)nullptr,
                     Wvt, b_val, (const float*)nullptr, (void*)vout);
  // k3: sampling + queue mean -> msd bf16
  hipLaunchKernelGGL(k3_sample, dim3(NQ / 2), dim3(256), 0, stream,
                     raw1, refp, vout, msdb);
  // k4: out = msd @ W_out + b_out + query  (40000x256 @ 256x256), bf16 A direct, fp32 out + resid
  hipLaunchKernelGGL((rb_gemm<256, 256, 0, 0, true>),
                     dim3(1250), dim3(256), 0, stream,
                     (const void*)msdb, (const void*)nullptr, (const void*)nullptr,
                     Wot, b_out, query, (void*)out);
}

// Round 4
// 366.386 us; speedup vs baseline: 1.1348x; 1.0230x over previous
//
#include <hip/hip_runtime.h>
#include <math.h>

// Problem constants: EMBED=256, HEADS=8, LEVELS=1, POINTS=4, QUEUE=2, 200x200
#define NQ    40000
#define EMB   256
#define NHEAD 8
#define HDIM  32
#define HB    200
#define WB    200
#define NCOL  192     // 128 off cols + 64 aw cols

typedef __attribute__((ext_vector_type(8))) __bf16 bf16x8;
typedef __attribute__((ext_vector_type(4))) float f32x4;

static __device__ __forceinline__ unsigned short f2bf(float f) {
  unsigned u = __float_as_uint(f);
  u = u + 0x7fffu + ((u >> 16) & 1u);   // round-to-nearest-even
  return (unsigned short)(u >> 16);
}
static __device__ __forceinline__ float bf2f(unsigned short s) {
  return __uint_as_float(((unsigned)s) << 16);
}

// ---------------------------------------------------------------------------
// conv_w: transposed bf16 weights + combined bias (tiny, one-shot)
// ---------------------------------------------------------------------------
__global__ __launch_bounds__(256) void conv_w(
    const float* __restrict__ W_off, const float* __restrict__ b_off,
    const float* __restrict__ W_attn, const float* __restrict__ b_attn,
    const float* __restrict__ W_val, const float* __restrict__ W_out,
    unsigned short* __restrict__ Wc1t, unsigned short* __restrict__ Wvt,
    unsigned short* __restrict__ Wot, float* __restrict__ bc1)
{
  int idx = blockIdx.x * 256 + threadIdx.x;
  if (idx < 98304) {                       // Wc1t [192][512]
    int n = idx >> 9, k = idx & 511;
    float v = (n < 128) ? W_off[(size_t)k * 128 + n] : W_attn[(size_t)k * 64 + (n - 128)];
    Wc1t[idx] = f2bf(v);
  } else if (idx < 163840) {               // Wvt [256][256]
    int j = idx - 98304;
    int n = j >> 8, k = j & 255;
    Wvt[j] = f2bf(W_val[(size_t)k * 256 + n]);
  } else if (idx < 229376) {               // Wot [256][256]
    int j = idx - 163840;
    int n = j >> 8, k = j & 255;
    Wot[j] = f2bf(W_out[(size_t)k * 256 + n]);
  } else if (idx < 229568) {               // bc1 [192]
    int n = idx - 229376;
    bc1[n] = (n < 128) ? b_off[n] : b_attn[n - 128];
  }
}

// ---------------------------------------------------------------------------
// Register GEMM: C[M x N] = A[M x K] @ Bt[N x K]^T + bias.
// Round-4 structure: MLP-first. __launch_bounds__(256,4) gives the allocator
// 128 VGPRs (round-3's 44 VGPRs serialized all memory: 941 GB/s, 3.5% MFMA).
//   - Staging: batch-load ALL of a thread's float4s into registers, then
//     convert+ds_write (one latency exposure, not 8).
//   - K-loop: explicit prefetch-1 of B- and A-frags ahead of the MFMAs,
//     fully unrolled.
// A path: AMODE 0 = bf16 [M][K] direct; 1 = fp32 staged -> LDS; 2 = synth
// q2 = [value | query+query_pos] staged -> LDS. LDS tile XOR-swizzled in 16B
// chunks (slot = c ^ (r&7)) -> ds_read_b128 A-frags are 2-way max (free).
// Block = 256 thr = 4 waves, 1m x 4n: BM = 32, wave tile 32 x N/4.
// OMODE: 0 = fp32 direct store (+resid); 1 = bf16 via LDS transpose (buffer
// unioned with the A-tile; barrier separates the two uses).
// ---------------------------------------------------------------------------
template<int K, int N, int AMODE, int OMODE, bool RESID>
__global__ __launch_bounds__(256, 4) void rb_gemm(
    const void* __restrict__ Aptr, const void* __restrict__ Aq2a,
    const void* __restrict__ Aq2b, const unsigned short* __restrict__ Bt,
    const float* __restrict__ bias, const float* __restrict__ resid,
    void* __restrict__ outp)
{
  constexpr int NFR = N / 64;              // 16-col n-frags per wave
  constexpr int NP  = N + 8;
  constexpr int ATB = (AMODE != 0) ? 32 * K * 2 : 0;      // A-tile bytes
  constexpr int TRB = (OMODE == 1) ? 32 * NP * 2 : 0;     // transpose bytes
  constexpr int MXB = (ATB > TRB) ? ATB : TRB;
  constexpr int LDSB = (MXB > 64) ? MXB : 64;
  __shared__ __align__(16) char lds[LDSB];
  unsigned short* trn = (unsigned short*)lds;

  const int t = threadIdx.x;
  const int m0 = blockIdx.x * 32;
  const int wid = t >> 6, lane = t & 63;
  const int wn = wid * (N / 4);
  const int lr = lane & 15, quad = lane >> 4;

  auto cvt_store = [&](int r, int c, float4 f0, float4 f1) {
    union { unsigned short us[8]; uint4 v; } u;
    u.us[0] = f2bf(f0.x); u.us[1] = f2bf(f0.y);
    u.us[2] = f2bf(f0.z); u.us[3] = f2bf(f0.w);
    u.us[4] = f2bf(f1.x); u.us[5] = f2bf(f1.y);
    u.us[6] = f2bf(f1.z); u.us[7] = f2bf(f1.w);
    *(uint4*)(lds + (size_t)r * (K * 2) + ((c ^ (r & 7)) * 16)) = u.v;
  };

  // ---- A staging: fp32 global -> bf16 LDS tile, once per block ----
  if constexpr (AMODE == 1) {
    // 32 rows x 32 chunks; thread owns col chunk c = t&31, rows r0+8l.
    const int c = t & 31, r0 = t >> 5;
    float4 f[4][2];
    #pragma unroll
    for (int l = 0; l < 4; l++) {
      const float* s = (const float*)Aptr + (size_t)(m0 + r0 + 8 * l) * K + c * 8;
      f[l][0] = *(const float4*)s; f[l][1] = *(const float4*)(s + 4);
    }
    #pragma unroll
    for (int l = 0; l < 4; l++)
      cvt_store(r0 + 8 * l, c, f[l][0], f[l][1]);
    __syncthreads();
  } else if constexpr (AMODE == 2) {
    // 32 rows x 64 chunks; thread owns col chunk c = t&63, rows r0+4l.
    // Branch (c<32: value | c>=32: query+query_pos) is uniform per thread;
    // loads stay coalesced within each half-wave.
    const int c = t & 63, r0 = t >> 6;
    if (c < 32) {
      float4 f[8][2];
      #pragma unroll
      for (int l = 0; l < 8; l++) {
        const float* s = (const float*)Aptr + (size_t)(m0 + r0 + 4 * l) * 256 + c * 8;
        f[l][0] = *(const float4*)s; f[l][1] = *(const float4*)(s + 4);
      }
      #pragma unroll
      for (int l = 0; l < 8; l++)
        cvt_store(r0 + 4 * l, c, f[l][0], f[l][1]);
    } else {
      #pragma unroll
      for (int h = 0; h < 2; h++) {        // 2 batches of 4 rows (reg budget)
        float4 fq[4][2], fp[4][2];
        #pragma unroll
        for (int l = 0; l < 4; l++) {
          int r = r0 + 4 * (h * 4 + l);
          const float* sq = (const float*)Aq2a + (size_t)(m0 + r) * 256 + (c - 32) * 8;
          const float* sp = (const float*)Aq2b + (size_t)(m0 + r) * 256 + (c - 32) * 8;
          fq[l][0] = *(const float4*)sq; fq[l][1] = *(const float4*)(sq + 4);
          fp[l][0] = *(const float4*)sp; fp[l][1] = *(const float4*)(sp + 4);
        }
        #pragma unroll
        for (int l = 0; l < 4; l++) {
          int r = r0 + 4 * (h * 4 + l);
          float4 f0 = make_float4(fq[l][0].x + fp[l][0].x, fq[l][0].y + fp[l][0].y,
                                  fq[l][0].z + fp[l][0].z, fq[l][0].w + fp[l][0].w);
          float4 f1 = make_float4(fq[l][1].x + fp[l][1].x, fq[l][1].y + fp[l][1].y,
                                  fq[l][1].z + fp[l][1].z, fq[l][1].w + fp[l][1].w);
          cvt_store(r, c, f0, f1);
        }
      }
    }
    __syncthreads();
  }

  f32x4 acc[2][NFR];
  #pragma unroll
  for (int i = 0; i < 2; i++)
    #pragma unroll
    for (int n = 0; n < NFR; n++) acc[i][n] = (f32x4){0.f, 0.f, 0.f, 0.f};

  auto loadB = [&](bf16x8* dst, int k0) {
    #pragma unroll
    for (int n = 0; n < NFR; n++)
      dst[n] = *(const bf16x8*)(Bt + (size_t)(wn + n * 16 + lr) * K + k0 + quad * 8);
  };
  auto loadA = [&](bf16x8* dst, int k0) {
    if constexpr (AMODE == 0) {
      const unsigned short* A = (const unsigned short*)Aptr;
      #pragma unroll
      for (int i = 0; i < 2; i++)
        dst[i] = *(const bf16x8*)(A + (size_t)(m0 + lr + i * 16) * K + k0 + quad * 8);
    } else {
      const int cb = (k0 >> 3) + quad;
      const int sw = (cb ^ (lr & 7)) * 16;
      #pragma unroll
      for (int i = 0; i < 2; i++)
        dst[i] = *(const bf16x8*)(lds + (size_t)(lr + i * 16) * (K * 2) + sw);
    }
  };

  constexpr int NK = K / 32;
  bf16x8 bcur[NFR], af[2];
  loadB(bcur, 0);
  loadA(af, 0);
  #pragma unroll
  for (int ks = 0; ks < NK; ks++) {
    bf16x8 bnxt[NFR], anxt[2];
    if (ks + 1 < NK) {                     // prefetch next k-step ahead of MFMAs
      loadB(bnxt, (ks + 1) * 32);
      loadA(anxt, (ks + 1) * 32);
    }
    #pragma unroll
    for (int i = 0; i < 2; i++)
      #pragma unroll
      for (int n = 0; n < NFR; n++)
        acc[i][n] = __builtin_amdgcn_mfma_f32_16x16x32_bf16(af[i], bcur[n], acc[i][n], 0, 0, 0);
    if (ks + 1 < NK) {
      #pragma unroll
      for (int n = 0; n < NFR; n++) bcur[n] = bnxt[n];
      af[0] = anxt[0]; af[1] = anxt[1];
    }
  }

  // epilogue: C/D layout col=lane&15, row=quad*4+reg
  if constexpr (OMODE == 0) {
    #pragma unroll
    for (int i = 0; i < 2; i++) {
      int rowb = m0 + i * 16 + quad * 4;
      #pragma unroll
      for (int n = 0; n < NFR; n++) {
        int col = wn + n * 16 + lr;
        float bsv = bias[col];
        #pragma unroll
        for (int r = 0; r < 4; r++) {
          int rr = rowb + r;
          float v = acc[i][n][r] + bsv;
          if (RESID) v += resid[(size_t)rr * N + col];
          ((float*)outp)[(size_t)rr * N + col] = v;
        }
      }
    }
  } else {
    // bf16 out via LDS transpose -> full-line uint4 stores.
    if constexpr (AMODE != 0) __syncthreads();   // A-tile -> trn buffer reuse
    #pragma unroll
    for (int i = 0; i < 2; i++) {
      #pragma unroll
      for (int n = 0; n < NFR; n++) {
        int col = wn + n * 16 + lr;
        float bsv = bias[col];
        #pragma unroll
        for (int r = 0; r < 4; r++) {
          int rl = i * 16 + quad * 4 + r;
          trn[rl * NP + col] = f2bf(acc[i][n][r] + bsv);
        }
      }
    }
    __syncthreads();
    constexpr int NCH = (32 * N) / 2048;   // uint4 chunks per thread
    #pragma unroll
    for (int l = 0; l < NCH; l++) {
      int c = t + l * 256;
      int row = c / (N / 8);
      int coloff = (c % (N / 8)) * 8;
      uint4 d = *(const uint4*)(trn + row * NP + coloff);
      *(uint4*)((unsigned short*)outp + (size_t)(m0 + row) * N + coloff) = d;
    }
  }
}

// ---------------------------------------------------------------------------
// K3: deformable sampling + queue mean. 2 queries/block. raw1 bf16.
// ---------------------------------------------------------------------------
__global__ __launch_bounds__(256) void k3_sample(
    const unsigned short* __restrict__ raw1, const float* __restrict__ refp,
    const unsigned short* __restrict__ v, unsigned short* __restrict__ msd)
{
  __shared__ int4   sidx[2][64];
  __shared__ float4 swgt[2][64];
  const int t = threadIdx.x;
  const int q0 = blockIdx.x * 2;

  if (t < 128) {
    const int s = t >> 6, e = t & 63;
    const int b = e >> 5, h = (e >> 2) & 7, p = e & 3;
    const int q = q0 + s;
    const unsigned short* r = raw1 + (size_t)q * NCOL;
    float ox = bf2f(r[h * 16 + b * 8 + p * 2 + 0]);
    float oy = bf2f(r[h * 16 + b * 8 + p * 2 + 1]);
    float l0 = bf2f(r[128 + h * 8 + b * 4 + 0]);
    float l1 = bf2f(r[128 + h * 8 + b * 4 + 1]);
    float l2 = bf2f(r[128 + h * 8 + b * 4 + 2]);
    float l3 = bf2f(r[128 + h * 8 + b * 4 + 3]);
    float mx = fmaxf(fmaxf(l0, l1), fmaxf(l2, l3));
    float e0 = expf(l0 - mx), e1 = expf(l1 - mx);
    float e2 = expf(l2 - mx), e3 = expf(l3 - mx);
    float ssum = e0 + e1 + e2 + e3;
    float ep = (p == 0) ? e0 : (p == 1) ? e1 : (p == 2) ? e2 : e3;
    float aw = ep / ssum * 0.5f;          // fold queue-mean 0.5
    float rx = refp[((size_t)b * NQ + q) * 2 + 0];
    float ry = refp[((size_t)b * NQ + q) * 2 + 1];
    float px = rx * (float)WB + ox - 0.5f;
    float py = ry * (float)HB + oy - 0.5f;
    float x0f = floorf(px), y0f = floorf(py);
    float lx = px - x0f, ly = py - y0f;
    int x0 = (int)x0f, y0 = (int)y0f, x1 = x0 + 1, y1 = y0 + 1;
    int x0c = min(max(x0, 0), WB - 1), x1c = min(max(x1, 0), WB - 1);
    int y0c = min(max(y0, 0), HB - 1), y1c = min(max(y1, 0), HB - 1);
    float vx0 = ((unsigned)x0 < (unsigned)WB) ? 1.f : 0.f;
    float vx1 = ((unsigned)x1 < (unsigned)WB) ? 1.f : 0.f;
    float vy0 = ((unsigned)y0 < (unsigned)HB) ? 1.f : 0.f;
    float vy1 = ((unsigned)y1 < (unsigned)HB) ? 1.f : 0.f;
    const int pb = b * NQ;
    const int hb = h * HDIM;
    int4 ix;
    ix.x = (pb + y0c * WB + x0c) * EMB + hb;
    ix.y = (pb + y0c * WB + x1c) * EMB + hb;
    ix.z = (pb + y1c * WB + x0c) * EMB + hb;
    ix.w = (pb + y1c * WB + x1c) * EMB + hb;
    float4 wv;
    wv.x = aw * (1.f - lx) * (1.f - ly) * vx0 * vy0;
    wv.y = aw * lx * (1.f - ly) * vx1 * vy0;
    wv.z = aw * (1.f - lx) * ly * vx0 * vy1;
    wv.w = aw * lx * ly * vx1 * vy1;
    sidx[s][e] = ix;
    swgt[s][e] = wv;
  }
  __syncthreads();

  const int s = t >> 7, u = t & 127;
  const int h = u >> 4, d2 = u & 15;
  const unsigned short* vd = v + d2 * 2;
  float a0 = 0.f, a1 = 0.f;
  #pragma unroll
  for (int b = 0; b < 2; b++) {
    #pragma unroll
    for (int p = 0; p < 4; p++) {
      int ent = b * 32 + h * 4 + p;
      int4 ix = sidx[s][ent];
      float4 wv = swgt[s][ent];
      unsigned c00 = *(const unsigned*)(vd + ix.x);
      unsigned c10 = *(const unsigned*)(vd + ix.y);
      unsigned c01 = *(const unsigned*)(vd + ix.z);
      unsigned c11 = *(const unsigned*)(vd + ix.w);
      a0 += wv.x * __uint_as_float(c00 << 16);
      a1 += wv.x * __uint_as_float(c00 & 0xffff0000u);
      a0 += wv.y * __uint_as_float(c10 << 16);
      a1 += wv.y * __uint_as_float(c10 & 0xffff0000u);
      a0 += wv.z * __uint_as_float(c01 << 16);
      a1 += wv.z * __uint_as_float(c01 & 0xffff0000u);
      a0 += wv.w * __uint_as_float(c11 << 16);
      a1 += wv.w * __uint_as_float(c11 & 0xffff0000u);
    }
  }
  unsigned pack = ((unsigned)f2bf(a1) << 16) | (unsigned)f2bf(a0);
  *(unsigned*)(msd + (size_t)(q0 + s) * EMB + h * HDIM + d2 * 2) = pack;
}

// ---------------------------------------------------------------------------
extern "C" void kernel_launch(void* const* d_in, const int* in_sizes, int n_in,
                              void* d_out, int out_size, void* d_ws, size_t ws_size,
                              hipStream_t stream) {
  const float* query     = (const float*)d_in[0];
  const float* query_pos = (const float*)d_in[1];
  const float* value     = (const float*)d_in[2];
  const float* refp      = (const float*)d_in[3];
  // d_in[4]: spatial_shapes constant [200,200]
  const float* W_off  = (const float*)d_in[5];
  const float* b_off  = (const float*)d_in[6];
  const float* W_attn = (const float*)d_in[7];
  const float* b_attn = (const float*)d_in[8];
  const float* W_val  = (const float*)d_in[9];
  const float* b_val  = (const float*)d_in[10];
  const float* W_out  = (const float*)d_in[11];
  const float* b_out  = (const float*)d_in[12];
  float* out = (float*)d_out;

  char* ws = (char*)d_ws;
  unsigned short* raw1 = (unsigned short*)(ws);            // 40000*192*2 = 15,360,000
  unsigned short* vout = (unsigned short*)(ws + 15360000); // 80000*256*2 = 40,960,000
  unsigned short* msdb = (unsigned short*)(ws + 56320000); // 40000*256*2 = 20,480,000
  unsigned short* Wc1t = (unsigned short*)(ws + 76800000); // 192*512*2
  unsigned short* Wvt  = (unsigned short*)(ws + 76996608); // 256*256*2
  unsigned short* Wot  = (unsigned short*)(ws + 77127680); // 256*256*2
  float*          bc1  = (float*)(ws + 77258752);          // 192*4

  hipLaunchKernelGGL(conv_w, dim3(897), dim3(256), 0, stream,
                     W_off, b_off, W_attn, b_attn, W_val, W_out, Wc1t, Wvt, Wot, bc1);

  // k1: raw1 = q2 @ [W_off|W_attn] + bc1  (40000x512 @ 512x192), staged synth A, bf16 out
  hipLaunchKernelGGL((rb_gemm<512, 192, 2, 1, false>),
                     dim3(1250), dim3(256), 0, stream,
                     (const void*)value, (const void*)query, (const void*)query_pos,
                     Wc1t, bc1, (const float*)nullptr, (void*)raw1);
  // k2: v = value @ W_val + b_val  (80000x256 @ 256x256), staged fp32 A, bf16 out
  hipLaunchKernelGGL((rb_gemm<256, 256, 1, 1, false>),
                     dim3(2500), dim3(256), 0, stream,
                     (const void*)value, (const void*)nullptr, (const void*)nullptr,
                     Wvt, b_val, (const float*)nullptr, (void*)vout);
  // k3: sampling + queue mean -> msd bf16
  hipLaunchKernelGGL(k3_sample, dim3(NQ / 2), dim3(256), 0, stream,
                     raw1, refp, vout, msdb);
  // k4: out = msd @ W_out + b_out + query  (40000x256 @ 256x256), bf16 A direct, fp32 out + resid
  hipLaunchKernelGGL((rb_gemm<256, 256, 0, 0, true>),
                     dim3(1250), dim3(256), 0, stream,
                     (const void*)msdb, (const void*)nullptr, (const void*)nullptr,
                     Wot, b_out, query, (void*)out);
}